// Round 1
// baseline (7621.613 us; speedup 1.0000x reference)
//
#include <hip/hip_runtime.h>
#include <cstdint>
#include <cstddef>

// Elman RNN forward, MI355X fp32 baseline.
// B=64, T=512, I=512, H=1024.
// d_out layout: hidden [B][T][H] then last_h [B][H].

#define Bsz 64
#define Tsz 512
#define Isz 512
#define Hsz 1024

// ---------------------------------------------------------------------------
// Kernel 1: xp = emb @ Wx^T + bx   -> written into d_out's hidden region.
// M = B*T = 32768, N = H = 1024, K = I = 512. Tiles 128x128, TK=16.
// Grid 2048 (256 m-tiles x 8 n-tiles), 256 threads, 8x8 microtile.
// ---------------------------------------------------------------------------
__global__ __launch_bounds__(256) void xp_gemm_f32(
    const float* __restrict__ A,    // [32768][512] embeddings
    const float* __restrict__ Wx,   // [1024][512]
    const float* __restrict__ bx,   // [1024]
    float* __restrict__ out)        // [32768][1024]
{
    __shared__ float As[16][128];   // k-major
    __shared__ float Bs[16][128];

    const int bid = blockIdx.x;
    const int m0 = (bid >> 3) << 7;     // 256 m-tiles
    const int n0 = (bid & 7) << 7;      // 8 n-tiles
    const int tid = (int)threadIdx.x;
    const int tx = tid & 15;            // n direction
    const int ty = tid >> 4;            // m direction

    float acc[8][8];
#pragma unroll
    for (int i = 0; i < 8; ++i)
#pragma unroll
        for (int j = 0; j < 8; ++j) acc[i][j] = 0.f;

    for (int kk = 0; kk < Isz; kk += 16) {
        // Stage A,B tiles: 512 float4 each; thread does 2 of each.
#pragma unroll
        for (int s = 0; s < 2; ++s) {
            const int f4 = (s << 8) + tid;        // 0..511
            const int r  = f4 >> 2;               // row in tile 0..127
            const int kq = (f4 & 3) << 2;         // 0,4,8,12
            const float4 a = *(const float4*)(A  + (size_t)(m0 + r) * Isz + kk + kq);
            const float4 b = *(const float4*)(Wx + (size_t)(n0 + r) * Isz + kk + kq);
            As[kq + 0][r] = a.x; As[kq + 1][r] = a.y; As[kq + 2][r] = a.z; As[kq + 3][r] = a.w;
            Bs[kq + 0][r] = b.x; Bs[kq + 1][r] = b.y; Bs[kq + 2][r] = b.z; Bs[kq + 3][r] = b.w;
        }
        __syncthreads();
#pragma unroll
        for (int k = 0; k < 16; ++k) {
            const float4 a0 = *(const float4*)&As[k][ty * 8];
            const float4 a1 = *(const float4*)&As[k][ty * 8 + 4];
            const float4 b0 = *(const float4*)&Bs[k][tx * 8];
            const float4 b1 = *(const float4*)&Bs[k][tx * 8 + 4];
            const float ar[8] = {a0.x, a0.y, a0.z, a0.w, a1.x, a1.y, a1.z, a1.w};
            const float br[8] = {b0.x, b0.y, b0.z, b0.w, b1.x, b1.y, b1.z, b1.w};
#pragma unroll
            for (int i = 0; i < 8; ++i)
#pragma unroll
                for (int j = 0; j < 8; ++j)
                    acc[i][j] = fmaf(ar[i], br[j], acc[i][j]);
        }
        __syncthreads();
    }

    float bxr[8];
#pragma unroll
    for (int j = 0; j < 8; ++j) bxr[j] = bx[n0 + tx * 8 + j];

#pragma unroll
    for (int i = 0; i < 8; ++i) {
        const size_t row = (size_t)(m0 + ty * 8 + i) * Hsz + (size_t)(n0 + tx * 8);
        float4 o0, o1;
        o0.x = acc[i][0] + bxr[0]; o0.y = acc[i][1] + bxr[1];
        o0.z = acc[i][2] + bxr[2]; o0.w = acc[i][3] + bxr[3];
        o1.x = acc[i][4] + bxr[4]; o1.y = acc[i][5] + bxr[5];
        o1.z = acc[i][6] + bxr[6]; o1.w = acc[i][7] + bxr[7];
        *(float4*)(out + row)     = o0;
        *(float4*)(out + row + 4) = o1;
    }
}

// ---------------------------------------------------------------------------
// Kernel 2: persistent scan. h_t = tanh(xp_t + h_{t-1} @ Wh^T + bh), in place
// over d_out's hidden region; also writes last_h at the end.
//
// Grid 256 wg x 256 thr, 1 wg/CU, all co-resident.
// wg -> (bT = wg&7, jT = wg>>3): sync group bT = 8 batch rows (32 wgs that
// produce all 1024 channels for those rows); wg owns 32 output channels.
// Thread roles:
//   compute:   jg = tid>>5 (4-channel group), ks = tid&31 (k-lane, k = ks+32*i)
//              Wh chunk [4][32] kept in REGISTERS for all 512 steps.
//   reduction: rb = tid>>5 (batch row 0..7), rj = tid&31 (channel 0..31).
// Barrier: flags[256] in d_ws; spin on (flag < t) -- 0xAA poison is negative,
// so no init needed. h stores are agent-scope atomics (write-through past the
// per-XCD L2s); release flag after vmcnt(0)+syncthreads.
// ---------------------------------------------------------------------------
__global__ __launch_bounds__(256, 1) void rnn_scan_f32(
    const float* __restrict__ h0,    // [64][1024]
    const float* __restrict__ Wh,    // [1024][1024]
    const float* __restrict__ bh,    // [1024]
    float* __restrict__ out,         // hidden [64][512][1024] then last [64][1024]
    int* __restrict__ flags)         // [256] in d_ws (poisoned 0xAA each launch)
{
    // union: h-stage view  hs(bb,k)    = smem[bb*1024 + k]        (8192 floats)
    //        reduce view   red(row,ks) = smem[row*33 + ks]        (8448 floats)
    __shared__ float smem[8 * 32 * 33];

    const int wg  = (int)blockIdx.x;
    const int bT  = wg & 7;          // group (8 groups of 32 wgs)
    const int jT  = wg >> 3;         // 0..31 channel tile
    const int tid = (int)threadIdx.x;
    const int ks  = tid & 31;
    const int jg  = tid >> 5;        // 0..7

    // Wh chunk in registers: rows j = jT*32 + jg*4 + jj, cols k = ks + 32*i
    float whr[4][32];
#pragma unroll
    for (int jj = 0; jj < 4; ++jj) {
        const float* wrow = Wh + (size_t)(jT * 32 + jg * 4 + jj) * Hsz + ks;
#pragma unroll
        for (int i = 0; i < 32; ++i) whr[jj][i] = wrow[i * 32];
    }

    const float bias = bh[jT * 32 + ks];   // reduction-phase channel
    const int myflag = bT * 32 + jT;

    for (int t = 0; t < Tsz; ++t) {
        if (t > 0) {
            if (tid < 32) {
                while (__hip_atomic_load(&flags[bT * 32 + tid],
                                         __ATOMIC_RELAXED,
                                         __HIP_MEMORY_SCOPE_AGENT) < t) {}
            }
            __syncthreads();
            __builtin_amdgcn_fence(__ATOMIC_ACQUIRE, "agent");
        }

        // Stage h_{t-1} tile [8][1024] into LDS (coalesced float4 per row).
#pragma unroll
        for (int bb = 0; bb < 8; ++bb) {
            const float* src = (t == 0)
                ? (h0 + (size_t)(bT * 8 + bb) * Hsz)
                : (out + ((size_t)(bT * 8 + bb) * Tsz + (t - 1)) * Hsz);
            const float4 v = *(const float4*)(src + tid * 4);
            *(float4*)(smem + bb * 1024 + tid * 4) = v;
        }
        __syncthreads();

        // Partial dot products: pacc[bb][jj] = sum_{k=ks+32i} h[bb][k]*Wh[j][k]
        float pacc[8][4];
#pragma unroll
        for (int bb = 0; bb < 8; ++bb)
#pragma unroll
            for (int jj = 0; jj < 4; ++jj) pacc[bb][jj] = 0.f;

#pragma unroll
        for (int bb = 0; bb < 8; ++bb) {
#pragma unroll
            for (int i = 0; i < 32; ++i) {
                const float hv = smem[bb * 1024 + ks + i * 32];  // bank = ks: conflict-free
#pragma unroll
                for (int jj = 0; jj < 4; ++jj)
                    pacc[bb][jj] = fmaf(hv, whr[jj][i], pacc[bb][jj]);
            }
        }
        __syncthreads();   // all hs reads done; safe to overwrite union

        // Scatter partials: row = bb*32 + (jg*4+jj), padded stride 33.
#pragma unroll
        for (int bb = 0; bb < 8; ++bb)
#pragma unroll
            for (int jj = 0; jj < 4; ++jj)
                smem[(bb * 32 + jg * 4 + jj) * 33 + ks] = pacc[bb][jj];
        __syncthreads();

        // Final reduce: thread tid owns output row (rb=tid>>5, rj=tid&31) == row tid.
        float ssum = 0.f;
#pragma unroll
        for (int i = 0; i < 32; ++i) ssum += smem[tid * 33 + i];  // bank=(ks+i)%32: conflict-free

        const int b = bT * 8 + (tid >> 5);
        const int j = jT * 32 + ks;
        const size_t oidx = ((size_t)b * Tsz + t) * Hsz + j;

        const float z = out[oidx] + ssum + bias;   // xp + Wh·h + bh
        // tanh(z) = 1 - 2/(exp(2z)+1); stable for +/-inf of exp.
        const float e = __expf(2.f * z);
        const float h = 1.f - 2.f / (e + 1.f);

        __hip_atomic_store(&out[oidx], h, __ATOMIC_RELAXED, __HIP_MEMORY_SCOPE_AGENT);
        if (t == Tsz - 1)
            out[(size_t)Bsz * Tsz * Hsz + (size_t)b * Hsz + j] = h;

        asm volatile("s_waitcnt vmcnt(0)" ::: "memory");
        __syncthreads();
        if (tid == 0)
            __hip_atomic_store(&flags[myflag], t + 1,
                               __ATOMIC_RELEASE, __HIP_MEMORY_SCOPE_AGENT);
    }
}

// ---------------------------------------------------------------------------
extern "C" void kernel_launch(void* const* d_in, const int* in_sizes, int n_in,
                              void* d_out, int out_size, void* d_ws, size_t ws_size,
                              hipStream_t stream) {
    const float* emb = (const float*)d_in[0];
    const float* h0  = (const float*)d_in[1];
    const float* Wx  = (const float*)d_in[2];
    const float* bx  = (const float*)d_in[3];
    const float* Wh  = (const float*)d_in[4];
    const float* bh  = (const float*)d_in[5];
    float* out = (float*)d_out;
    int* flags = (int*)d_ws;   // 256 ints; poisoned 0xAA => negative => spin-safe

    hipLaunchKernelGGL(xp_gemm_f32, dim3(2048), dim3(256), 0, stream,
                       emb, Wx, bx, out);
    hipLaunchKernelGGL(rnn_scan_f32, dim3(256), dim3(256), 0, stream,
                       h0, Wh, bh, out, flags);
}